// Round 3
// baseline (3914.456 us; speedup 1.0000x reference)
//
#include <hip/hip_runtime.h>
#include <cstdint>
#include <cstddef>

// EP-LSTM, B=64 T=1024 D=256 H=256.  I/O dtype: FP32 (per reference file).
// Identity: pre = x@(Wx + W_in@We) + h@(Wh - We) + b   (e@We eliminated).
//
// d_ws is NOT used (round-1/2 hardening).  All scratch lives in the y-region
// of d_out (67,108,864 bytes), which is only written by the FINAL kernel:
//   Gc     @ y+0        : [64*256][1024] bf16 = 33,554,432 B (per-chunk G)
//   At     @ y+33554432 : [1024][256] bf16    = 524,288  (A^T = (Wx+W_in@We)^T)
//   Rres   @ y+34078720 : [128][512] u32      = 262,144  (f16x2 pairs, cols 0..511)
//   Rstr   @ y+34340864 : [32][512] uint4     = 262,144  (f16x2 quads, cols 512..1023)
//   stateH @ y+34603008 : [64][128] u32       = 32,768   (h packed f16x2, chunk carry)
//   stateC @ y+34635776 : [64][256] f32       = 65,536   (c fp32, chunk carry)
// Final gemm_y reads hseq + W_out (input) only, so overwriting y is safe.

typedef unsigned int   u32;
typedef unsigned short u16;
typedef float  f32x4  __attribute__((ext_vector_type(4)));
typedef short  bf16x8 __attribute__((ext_vector_type(8)));
typedef _Float16 h2_t __attribute__((ext_vector_type(2)));

__device__ __forceinline__ u16 f2bf(float f){
  union { float f; u32 i; } v; v.f = f;
  u32 u = v.i; u32 r = u + 0x7fffu + ((u >> 16) & 1u);
  return (u16)(r >> 16);
}
__device__ __forceinline__ float bf2f(u16 u){
  union { u32 i; float f; } v; v.i = ((u32)u) << 16; return v.f;
}
__device__ __forceinline__ h2_t as_h2(u32 u){
  union { u32 u; h2_t h; } c; c.u = u; return c.h;
}
__device__ __forceinline__ u32 pack_h2(float lo, float hi){
  h2_t h; h.x = (_Float16)lo; h.y = (_Float16)hi;
  union { h2_t h; u32 u; } c; c.h = h; return c.u;
}

#if defined(__has_builtin)
#if __has_builtin(__builtin_amdgcn_fdot2)
#define HAVE_FDOT2 1
#endif
#endif

__device__ __forceinline__ float dot2acc(u32 w, u32 h, float acc){
#ifdef HAVE_FDOT2
  return __builtin_amdgcn_fdot2(as_h2(w), as_h2(h), acc, false);
#else
  h2_t a = as_h2(w), b = as_h2(h);
  acc += (float)a.x * (float)b.x;
  acc += (float)a.y * (float)b.y;
  return acc;
#endif
}

__device__ __forceinline__ float sigf(float x){
  return __builtin_amdgcn_rcpf(1.f + __expf(-x));
}
__device__ __forceinline__ float tanhf_(float x){
  return 2.f * __builtin_amdgcn_rcpf(1.f + __expf(-2.f * x)) - 1.f;
}

// ---------- prep: At[n][k] = Wx[kg][k][j] + sum_m W_in[k][m]*We[kg][m][j] ----------
__global__ void prep_A(const float* __restrict__ Win, const float* __restrict__ Wx,
                       const float* __restrict__ We, u16* __restrict__ At){
  int n  = blockIdx.x;            // 0..1023 (kg*256 + j)
  int kg = n >> 8, j = n & 255;
  int k  = threadIdx.x;           // 0..255 = d
  __shared__ float wec[256];
  wec[k] = We[kg * 65536 + k * 256 + j];   // We[kg][m=k][j]
  __syncthreads();
  float s = Wx[kg * 65536 + k * 256 + j];
  const float* wrow = Win + k * 256;
  #pragma unroll 8
  for (int m = 0; m < 256; m++) s += wrow[m] * wec[m];
  At[n * 256 + k] = f2bf(s);
}

// ---------- prep: R = Wh - We, packed f16x2 by k-pairs, split resident/streamed ----------
__global__ void prep_R(const float* __restrict__ Wh, const float* __restrict__ We,
                       u32* __restrict__ Rres, u32* __restrict__ Rstrw){
  int g   = blockIdx.x * 512 + threadIdx.x;   // 0..131071
  int k2  = g >> 10, col = g & 1023;
  int kg  = col >> 8, j = col & 255;
  int base = kg * 65536 + (2 * k2) * 256 + j;
  float lo = Wh[base]       - We[base];
  float hi = Wh[base + 256] - We[base + 256];
  u32 u = pack_h2(lo, hi);
  if (col < 512) {
    Rres[k2 * 512 + col] = u;
  } else {
    int q = k2 >> 2, e = k2 & 3;
    Rstrw[(q * 512 + (col - 512)) * 4 + e] = u;
  }
}

// ---------- gemm_g: Gc[m][n] = bf16( x[srow(m)][:] ) . At[n][:] + bg[n] ----------
// m in [0,16384): b = m>>8, tt = m&255, srow = b*1024 + t0 + tt.  N = 1024.
__global__ __launch_bounds__(256, 2) void gemm_g(
    const float* __restrict__ X, const u16* __restrict__ At,
    u16* __restrict__ Gc, const float* __restrict__ bg, int t0){
  __shared__ u16 As[64 * 256];
  __shared__ u16 Bs[64 * 256];
  int tid = threadIdx.x;
  int bm = blockIdx.x, bn = blockIdx.y;
  int r = tid >> 2, q = tid & 3;
  int m = bm * 64 + r;
  long srow = (long)(m >> 8) * 1024 + t0 + (m & 255);
  const float* ga = X + srow * 256 + q * 64;
  const u16*   gb = At + ((long)bn * 64 + r) * 256 + q * 64;
  u16* la = As + r * 256 + q * 64;
  u16* lb = Bs + r * 256 + q * 64;
  #pragma unroll
  for (int i = 0; i < 8; i++){
    float4 f0 = *(const float4*)(ga + i * 8);
    float4 f1 = *(const float4*)(ga + i * 8 + 4);
    union { u16 h[8]; uint4 v; } pk;
    pk.h[0] = f2bf(f0.x); pk.h[1] = f2bf(f0.y); pk.h[2] = f2bf(f0.z); pk.h[3] = f2bf(f0.w);
    pk.h[4] = f2bf(f1.x); pk.h[5] = f2bf(f1.y); pk.h[6] = f2bf(f1.z); pk.h[7] = f2bf(f1.w);
    *(uint4*)(la + i * 8) = pk.v;
    *(uint4*)(lb + i * 8) = *(const uint4*)(gb + i * 8);
  }
  __syncthreads();

  int wave = tid >> 6, lane = tid & 63;
  int wm = (wave & 1) * 32, wn = (wave >> 1) * 32;
  int fr = lane & 15, quad = lane >> 4;
  f32x4 acc00 = {0,0,0,0}, acc01 = {0,0,0,0}, acc10 = {0,0,0,0}, acc11 = {0,0,0,0};
  const u16* pa0 = As + (wm + fr) * 256 + quad * 8;
  const u16* pa1 = pa0 + 16 * 256;
  const u16* pb0 = Bs + (wn + fr) * 256 + quad * 8;
  const u16* pb1 = pb0 + 16 * 256;
  #pragma unroll
  for (int k = 0; k < 256; k += 32){
    bf16x8 a0 = *(const bf16x8*)(pa0 + k);
    bf16x8 a1 = *(const bf16x8*)(pa1 + k);
    bf16x8 b0 = *(const bf16x8*)(pb0 + k);
    bf16x8 b1 = *(const bf16x8*)(pb1 + k);
    acc00 = __builtin_amdgcn_mfma_f32_16x16x32_bf16(a0, b0, acc00, 0, 0, 0);
    acc01 = __builtin_amdgcn_mfma_f32_16x16x32_bf16(a0, b1, acc01, 0, 0, 0);
    acc10 = __builtin_amdgcn_mfma_f32_16x16x32_bf16(a1, b0, acc10, 0, 0, 0);
    acc11 = __builtin_amdgcn_mfma_f32_16x16x32_bf16(a1, b1, acc11, 0, 0, 0);
  }
  // C/D layout: col = lane&15, row = (lane>>4)*4 + reg  [m89-verified]
  int cr = quad * 4, cc = fr;
  long rowbase = (long)bm * 64 + wm + cr;
  long colbase = (long)bn * 64 + wn + cc;
  float bias0 = bg[colbase];
  float bias1 = bg[colbase + 16];
  #pragma unroll
  for (int e = 0; e < 4; e++){
    long r0 = rowbase + e, r1 = r0 + 16;
    Gc[r0 * 1024 + colbase]      = f2bf(acc00[e] + bias0);
    Gc[r0 * 1024 + colbase + 16] = f2bf(acc01[e] + bias1);
    Gc[r1 * 1024 + colbase]      = f2bf(acc10[e] + bias0);
    Gc[r1 * 1024 + colbase + 16] = f2bf(acc11[e] + bias1);
  }
}

// ---------- gemm_y: Y[m][n] = hseq[m][:] . W_out[:][n] + bo[n]   (M=65536,N=256) ----------
__global__ __launch_bounds__(256, 2) void gemm_y(
    const float* __restrict__ Hs, const float* __restrict__ Wo,
    float* __restrict__ Y, const float* __restrict__ bo){
  __shared__ u16 As[64 * 256];
  __shared__ u16 Bs[64 * 256];
  int tid = threadIdx.x;
  int bm = blockIdx.x, bn = blockIdx.y;
  int r = tid >> 2, q = tid & 3;
  const float* ga = Hs + ((long)bm * 64 + r) * 256 + q * 64;
  u16* la = As + r * 256 + q * 64;
  #pragma unroll
  for (int i = 0; i < 8; i++){
    float4 f0 = *(const float4*)(ga + i * 8);
    float4 f1 = *(const float4*)(ga + i * 8 + 4);
    union { u16 h[8]; uint4 v; } pk;
    pk.h[0] = f2bf(f0.x); pk.h[1] = f2bf(f0.y); pk.h[2] = f2bf(f0.z); pk.h[3] = f2bf(f0.w);
    pk.h[4] = f2bf(f1.x); pk.h[5] = f2bf(f1.y); pk.h[6] = f2bf(f1.z); pk.h[7] = f2bf(f1.w);
    *(uint4*)(la + i * 8) = pk.v;
  }
  // B tile: Bs[row n=r][k] = W_out[k][bn*64+r], k = q*64 + i (strided, L2-resident)
  int ncol = bn * 64 + r;
  u16* lb = Bs + r * 256 + q * 64;
  #pragma unroll 8
  for (int i = 0; i < 64; i++) lb[i] = f2bf(Wo[(q * 64 + i) * 256 + ncol]);
  __syncthreads();

  int wave = tid >> 6, lane = tid & 63;
  int wm = (wave & 1) * 32, wn = (wave >> 1) * 32;
  int fr = lane & 15, quad = lane >> 4;
  f32x4 acc00 = {0,0,0,0}, acc01 = {0,0,0,0}, acc10 = {0,0,0,0}, acc11 = {0,0,0,0};
  const u16* pa0 = As + (wm + fr) * 256 + quad * 8;
  const u16* pa1 = pa0 + 16 * 256;
  const u16* pb0 = Bs + (wn + fr) * 256 + quad * 8;
  const u16* pb1 = pb0 + 16 * 256;
  #pragma unroll
  for (int k = 0; k < 256; k += 32){
    bf16x8 a0 = *(const bf16x8*)(pa0 + k);
    bf16x8 a1 = *(const bf16x8*)(pa1 + k);
    bf16x8 b0 = *(const bf16x8*)(pb0 + k);
    bf16x8 b1 = *(const bf16x8*)(pb1 + k);
    acc00 = __builtin_amdgcn_mfma_f32_16x16x32_bf16(a0, b0, acc00, 0, 0, 0);
    acc01 = __builtin_amdgcn_mfma_f32_16x16x32_bf16(a0, b1, acc01, 0, 0, 0);
    acc10 = __builtin_amdgcn_mfma_f32_16x16x32_bf16(a1, b0, acc10, 0, 0, 0);
    acc11 = __builtin_amdgcn_mfma_f32_16x16x32_bf16(a1, b1, acc11, 0, 0, 0);
  }
  int cr = quad * 4, cc = fr;
  long rowbase = (long)bm * 64 + wm + cr;
  long colbase = (long)bn * 64 + wn + cc;
  float bias0 = bo[colbase];
  float bias1 = bo[colbase + 16];
  #pragma unroll
  for (int e = 0; e < 4; e++){
    long r0 = rowbase + e, r1 = r0 + 16;
    Y[r0 * 256 + colbase]      = acc00[e] + bias0;
    Y[r0 * 256 + colbase + 16] = acc01[e] + bias1;
    Y[r1 * 256 + colbase]      = acc10[e] + bias0;
    Y[r1 * 256 + colbase + 16] = acc11[e] + bias1;
  }
}

// ---------- recurrent scan over one 256-step chunk; one WG per batch element ----------
__global__ __launch_bounds__(512, 2) void scan_chunk(
    const u32* __restrict__ Rres, const uint4* __restrict__ Rstr,
    const u16* __restrict__ Gc,
    const float* __restrict__ h0, const float* __restrict__ c0,
    u32* __restrict__ stateH, float* __restrict__ stateC,
    float* __restrict__ hseq, float* __restrict__ cseq, int t0){
  const int CT = 256;
  int b = blockIdx.x;
  int j = threadIdx.x;

  // resident weights: column j, 128 f16x2 words
  u32 w[128];
  #pragma unroll
  for (int k2 = 0; k2 < 128; k2++) w[k2] = Rres[k2 * 512 + j];

  __shared__ __align__(16) u32 hbuf[128];   // h as f16x2
  __shared__ float xch[1024];               // pre exchange / h exchange

  float cst = 0.f;
  if (t0 == 0){
    if (j < 128) hbuf[j] = pack_h2(h0[b * 256 + 2 * j], h0[b * 256 + 2 * j + 1]);
    if (j < 256) cst = c0[b * 256 + j];
  } else {
    if (j < 128) hbuf[j] = stateH[b * 128 + j];
    if (j < 256) cst = stateC[b * 256 + j];
  }

  const u16* Grow = Gc + (size_t)b * CT * 1024;
  u16 ga = Grow[j], gb = Grow[512 + j];
  const uint4* Rsj = Rstr + j;
  __syncthreads();

  for (int tt = 0; tt < CT; tt++){
    const u16* Gn = Grow + (size_t)(tt + 1 < CT ? tt + 1 : tt) * 1024;
    u16 gan = Gn[j], gbn = Gn[512 + j];

    float acc0 = bf2f(ga), acc1 = bf2f(gb);   // bias folded into G
    #pragma unroll
    for (int qk = 0; qk < 32; qk++){
      uint4 ws4 = Rsj[qk * 512];
      uint4 hh  = *(const uint4*)(hbuf + qk * 4);
      acc0 = dot2acc(w[4*qk + 0], hh.x, acc0);
      acc0 = dot2acc(w[4*qk + 1], hh.y, acc0);
      acc0 = dot2acc(w[4*qk + 2], hh.z, acc0);
      acc0 = dot2acc(w[4*qk + 3], hh.w, acc0);
      acc1 = dot2acc(ws4.x, hh.x, acc1);
      acc1 = dot2acc(ws4.y, hh.y, acc1);
      acc1 = dot2acc(ws4.z, hh.z, acc1);
      acc1 = dot2acc(ws4.w, hh.w, acc1);
    }
    xch[j] = acc0; xch[512 + j] = acc1;
    __syncthreads();

    if (j < 256){
      float f  = sigf(xch[j]);
      float ii = sigf(xch[256 + j]);
      float o  = sigf(xch[512 + j]);
      float g  = tanhf_(xch[768 + j]);
      cst = f * cst + ii * g;
      float hv = o * tanhf_(cst);
      size_t orow = ((size_t)b * 1024 + t0 + tt) * 256 + j;
      hseq[orow] = hv;
      cseq[orow] = cst;
      xch[j] = hv;
    }
    __syncthreads();

    if (j < 128) hbuf[j] = pack_h2(xch[2 * j], xch[2 * j + 1]);
    ga = gan; gb = gbn;
    __syncthreads();
  }

  if (j < 128) stateH[b * 128 + j] = hbuf[j];
  if (j < 256) stateC[b * 256 + j] = cst;
}

extern "C" void kernel_launch(void* const* d_in, const int* in_sizes, int n_in,
                              void* d_out, int out_size, void* d_ws, size_t ws_size,
                              hipStream_t stream){
  const float* x   = (const float*)d_in[0];
  const float* h0  = (const float*)d_in[1];
  const float* c0  = (const float*)d_in[2];
  const float* Win = (const float*)d_in[3];
  const float* Wx  = (const float*)d_in[4];
  const float* Wh  = (const float*)d_in[5];
  const float* We  = (const float*)d_in[6];
  const float* bg  = (const float*)d_in[7];
  const float* Wo  = (const float*)d_in[8];
  const float* bo  = (const float*)d_in[9];

  float* y    = (float*)d_out;
  float* hseq = y + 16777216;
  float* cseq = y + 33554432;

  // scratch inside the y-region (written only by the final gemm_y)
  char* yb = (char*)d_out;
  u16*   Gc     = (u16*)(yb);
  u16*   At     = (u16*)(yb + 33554432);
  u32*   Rres   = (u32*)(yb + 34078720);
  uint4* Rstr   = (uint4*)(yb + 34340864);
  u32*   stateH = (u32*)(yb + 34603008);
  float* stateC = (float*)(yb + 34635776);

  prep_A<<<1024, 256, 0, stream>>>(Win, Wx, We, At);
  prep_R<<<256, 512, 0, stream>>>(Wh, We, Rres, (u32*)Rstr);

  for (int c = 0; c < 4; c++){
    int t0 = c * 256;
    gemm_g<<<dim3(256, 16), 256, 0, stream>>>(x, At, Gc, bg, t0);
    scan_chunk<<<64, 512, 0, stream>>>(Rres, Rstr, Gc, h0, c0,
                                       stateH, stateC, hseq, cseq, t0);
  }

  gemm_y<<<dim3(1024, 4), 256, 0, stream>>>(hseq, Wo, y, bo);
}